// Round 14
// baseline (677.374 us; speedup 1.0000x reference)
//
#include <hip/hip_runtime.h>
#include <hip/hip_bf16.h>
#include <math.h>

typedef __attribute__((ext_vector_type(8))) short s16x8;
typedef __attribute__((ext_vector_type(4))) float f32x4;

static constexpr float cSCALE = 0.17677669529663687f; // 32^-0.5

__device__ __forceinline__ float bf2f(unsigned short u) {
    union { unsigned int i; float f; } c; c.i = ((unsigned int)u) << 16; return c.f;
}
__device__ __forceinline__ unsigned short f2bf(float f) {
    union { float f; unsigned int i; } c; c.f = f;
    unsigned int r = c.i + (0x7fffu + ((c.i >> 16) & 1u));
    return (unsigned short)(r >> 16);
}
// HW packed f32->bf16 (RNE): lo = a, hi = b
__device__ __forceinline__ unsigned pk2(float a, float b) {
    unsigned r;
    asm("v_cvt_pk_bf16_f32 %0, %1, %2" : "=v"(r) : "v"(a), "v"(b));
    return r;
}
__device__ __forceinline__ s16x8 cvt8(const float4 a, const float4 b) {
    s16x8 r;
    r[0]=(short)f2bf(a.x); r[1]=(short)f2bf(a.y); r[2]=(short)f2bf(a.z); r[3]=(short)f2bf(a.w);
    r[4]=(short)f2bf(b.x); r[5]=(short)f2bf(b.y); r[6]=(short)f2bf(b.z); r[7]=(short)f2bf(b.w);
    return r;
}
__device__ __forceinline__ float gelu_f(float t) {
    const float u = 1.5957691216057308f * t * (1.0f + 0.044715f * t * t);
    return t / (1.0f + __expf(-u));
}

#define GLDS16(gp, lp) __builtin_amdgcn_global_load_lds( \
    (const __attribute__((address_space(1))) void*)(gp), \
    (__attribute__((address_space(3))) void*)(lp), 16, 0, 0)

// In-register LayerNorm of one 192-col row -> 6 MFMA A-fragments (cvt_pk packed).
__device__ __forceinline__ void ln_frag(const float* __restrict__ rowp,
                                        const float* __restrict__ g,
                                        const float* __restrict__ b,
                                        int hi, s16x8* xa)
{
    float4 v[12];
    #pragma unroll
    for (int k = 0; k < 6; ++k) {
        v[2*k]   = *(const float4*)(rowp + k*32 + hi*8);
        v[2*k+1] = *(const float4*)(rowp + k*32 + hi*8 + 4);
    }
    float sm = 0.f, sq = 0.f;
    #pragma unroll
    for (int i = 0; i < 12; ++i) {
        sm += (v[i].x + v[i].y) + (v[i].z + v[i].w);
        sq += (v[i].x*v[i].x + v[i].y*v[i].y) + (v[i].z*v[i].z + v[i].w*v[i].w);
    }
    sm += __shfl_xor(sm, 16); sq += __shfl_xor(sq, 16);
    sm += __shfl_xor(sm, 32); sq += __shfl_xor(sq, 32);
    const float mean = sm * (1.0f/192.0f);
    const float rstd = rsqrtf(sq * (1.0f/192.0f) - mean*mean + 1e-5f);
    #pragma unroll
    for (int k = 0; k < 6; ++k) {
        const float4 ga = *(const float4*)(g + k*32 + hi*8);
        const float4 gb = *(const float4*)(g + k*32 + hi*8 + 4);
        const float4 ba = *(const float4*)(b + k*32 + hi*8);
        const float4 bb = *(const float4*)(b + k*32 + hi*8 + 4);
        union { s16x8 s; unsigned u[4]; } r;
        r.u[0] = pk2((v[2*k].x  -mean)*rstd*ga.x + ba.x, (v[2*k].y  -mean)*rstd*ga.y + ba.y);
        r.u[1] = pk2((v[2*k].z  -mean)*rstd*ga.z + ba.z, (v[2*k].w  -mean)*rstd*ga.w + ba.w);
        r.u[2] = pk2((v[2*k+1].x-mean)*rstd*gb.x + bb.x, (v[2*k+1].y-mean)*rstd*gb.y + bb.y);
        r.u[3] = pk2((v[2*k+1].z-mean)*rstd*gb.z + bb.z, (v[2*k+1].w-mean)*rstd*gb.w + bb.w);
        xa[k] = r.s;
    }
}

// ============ Prep (merged): pack weights + fold rpb/mask bias into d_ws ============
__global__ __launch_bounds__(256)
void pack_all(const float* __restrict__ qkvw, const float* __restrict__ pw,
              const float* __restrict__ f1w, const float* __restrict__ f2w,
              const float* __restrict__ mask, const float* __restrict__ rpb,
              unsigned short* __restrict__ o, unsigned short* __restrict__ ob)
{
    if (blockIdx.x < 216) {
        const int t = blockIdx.x * 256 + threadIdx.x; // 0..55295
        const int lane = t & 63, f = t >> 6;
        const int ln = lane & 15, ko = (lane >> 4) * 8;
        const float* src;
        if (f < 216) {
            const int h = f / 36, r = f - h * 36, nf = r / 6, kf = r - nf * 6;
            src = qkvw + (size_t)((nf >> 1) * 192 + h * 32 + (nf & 1) * 16 + ln) * 192 + kf * 32 + ko;
        } else if (f < 288) {
            const int g = f - 216, h = g / 12, nf = g - h * 12;
            src = pw + (size_t)(nf * 16 + ln) * 192 + h * 32 + ko;
        } else {
            const int g = f - 288;
            const int c = g / 24, r24 = g - c * 24;
            if (r24 < 12) {
                const int nf = r24 / 6, kf = r24 - nf * 6;
                src = f1w + (size_t)(c * 32 + nf * 16 + ln) * 192 + kf * 32 + ko;
            } else {
                const int nf = r24 - 12;
                src = f2w + (size_t)(nf * 16 + ln) * 768 + c * 32 + ko;
            }
        }
        *(s16x8*)(o + (size_t)t * 8) = cvt8(*(const float4*)src, *(const float4*)(src + 4));
    } else {
        const int bid = blockIdx.x - 216;            // 0..383
        const int wi = bid / 6, h = bid - wi * 6;
        for (int t = threadIdx.x; t < 49 * 64; t += 256) {
            const int n = t >> 6, mm = t & 63;
            const int ln = mm >> 2, nf = mm & 3;
            const int m = nf * 16 + ln;
            float v = -100.0f;
            if (m < 49) {
                const int p1 = n / 7, q1 = n - p1 * 7, p2 = m / 7, q2 = m - p2 * 7;
                const int ridx = (p1 - p2 + 6) * 13 + (q1 - q2 + 6);
                v = rpb[ridx * 6 + h] + mask[(size_t)wi * 2401 + n * 49 + m];
            }
            ob[(size_t)(wi * 6 + h) * 3136 + t] = f2bf(v);
        }
    }
}

// ============ Kernel A: LN1 + shift/window + MFMA attention + proj + residual ============
// (256,2): ~256 VGPR budget so ALL 36 QKV B-fragments batch in flight per head.
__global__ __launch_bounds__(256, 2)
void swin_attn(const float* __restrict__ x, const float* __restrict__ g1,
               const float* __restrict__ b1, const unsigned short* __restrict__ wp,
               const unsigned short* __restrict__ bias_g,
               const float* __restrict__ qkvb, const float* __restrict__ pb,
               float* __restrict__ y)
{
    __shared__ __align__(16) unsigned short q_[64][40];      // 5120 (wave-private rows)
    __shared__ __align__(16) unsigned short o_[64][40];      // 5120 (wave-private rows)
    __shared__ __align__(16) unsigned short k2_[2][64][40];  // 10240 (cross-wave, dbuf)
    __shared__ __align__(16) unsigned short vt2_[2][32][72]; // 9216 (cross-wave, dbuf)
    __shared__ __align__(16) unsigned short p_[64][72];      // 9216 (wave-private rows)
    // total 38912 B

    const s16x8* wv = (const s16x8*)wp;
    const int w  = blockIdx.x;
    const int bb = w >> 6, wi = w & 63;
    const int wh = wi >> 3, ww = wi & 7;
    const int tid = threadIdx.x, lane = tid & 63, wave = tid >> 6;
    const int ln = lane & 15, hi = lane >> 4, ko = hi * 8, ro = hi * 4;
    const int m0 = wave * 16;

    // ---- LN1 fully in registers ----
    s16x8 xa[6];
    {
        const int t = m0 + ln;
        const int p = t / 7, q7 = t - p * 7;
        int i2 = wh * 7 + p + 3;  if (i2 >= 56) i2 -= 56;
        int j2 = ww * 7 + q7 + 3; if (j2 >= 56) j2 -= 56;
        const float* xr = x + ((size_t)(bb * 56 + i2) * 56 + j2) * 192;
        ln_frag(xr, g1, b1, hi, xa);
        if (t >= 49) {
            #pragma unroll
            for (int k = 0; k < 6; ++k) xa[k] = s16x8{0,0,0,0,0,0,0,0};
        }
    }

    // QKV for head hh into buffer hh&1; ALL 36 B-fragments batched (one latency pay)
    auto qkv_head = [&](int hh) {
        const s16x8* wq = wv + ((size_t)(hh * 36) << 6);
        s16x8 bf36[36];
        #pragma unroll
        for (int t = 0; t < 36; ++t) bf36[t] = wq[t * 64 + lane];   // t = nf*6+kf
        #pragma unroll
        for (int nf = 0; nf < 6; ++nf) {
            f32x4 a = f32x4{0.f,0.f,0.f,0.f};
            #pragma unroll
            for (int kf = 0; kf < 6; ++kf)
                a = __builtin_amdgcn_mfma_f32_16x16x32_bf16(xa[kf], bf36[nf * 6 + kf], a, 0, 0, 0);
            const int col = nf * 16 + ln;
            if (nf < 2) {
                const float bq = qkvb[hh*32 + col];
                const unsigned lo = pk2((a[0]+bq)*cSCALE, (a[1]+bq)*cSCALE);
                const unsigned hh2 = pk2((a[2]+bq)*cSCALE, (a[3]+bq)*cSCALE);
                q_[m0+ro+0][col] = (unsigned short)lo;  q_[m0+ro+1][col] = (unsigned short)(lo >> 16);
                q_[m0+ro+2][col] = (unsigned short)hh2; q_[m0+ro+3][col] = (unsigned short)(hh2 >> 16);
            } else if (nf < 4) {
                const float bk = qkvb[192 + hh*32 + col - 32];
                const unsigned lo = pk2(a[0]+bk, a[1]+bk), hh2 = pk2(a[2]+bk, a[3]+bk);
                k2_[hh&1][m0+ro+0][col-32] = (unsigned short)lo;  k2_[hh&1][m0+ro+1][col-32] = (unsigned short)(lo >> 16);
                k2_[hh&1][m0+ro+2][col-32] = (unsigned short)hh2; k2_[hh&1][m0+ro+3][col-32] = (unsigned short)(hh2 >> 16);
            } else {
                const float bv = qkvb[384 + hh*32 + col - 64];
                const unsigned lo = pk2(a[0]+bv, a[1]+bv), hh2 = pk2(a[2]+bv, a[3]+bv);
                vt2_[hh&1][col-64][m0+ro+0] = (unsigned short)lo;  vt2_[hh&1][col-64][m0+ro+1] = (unsigned short)(lo >> 16);
                vt2_[hh&1][col-64][m0+ro+2] = (unsigned short)hh2; vt2_[hh&1][col-64][m0+ro+3] = (unsigned short)(hh2 >> 16);
            }
        }
    };

    qkv_head(0);

    f32x4 accp[12];
    #pragma unroll
    for (int i = 0; i < 12; ++i) accp[i] = f32x4{0.f,0.f,0.f,0.f};

    // bias prefetch for head 0 (clamped rows; garbage rows discarded at epilogue)
    uint2 bb4[4];
    {
        const unsigned short* bg = bias_g + (size_t)(wi * 6) * 3136;
        #pragma unroll
        for (int i = 0; i < 4; ++i) {
            const int nc = min(m0 + ro + i, 48);
            bb4[i] = *(const uint2*)(bg + nc * 64 + ln * 4);
        }
    }

    for (int h = 0; h < 6; ++h) {
        __syncthreads();   // k2_/vt2_[h&1] visible to all waves

        // ---- S = Q @ K^T + fused bias (mask baked); softmax without max-reduce ----
        f32x4 s4[4];
        {
            const s16x8 aq = *(const s16x8*)&q_[m0 + ln][ko];
            #pragma unroll
            for (int nf = 0; nf < 4; ++nf) {
                const s16x8 bk = *(const s16x8*)&k2_[h & 1][nf * 16 + ln][ko];
                s4[nf] = __builtin_amdgcn_mfma_f32_16x16x32_bf16(aq, bk, f32x4{0.f,0.f,0.f,0.f}, 0, 0, 0);
            }
        }
        float inv4[4];
        #pragma unroll
        for (int i = 0; i < 4; ++i) {
            const int n = m0 + ro + i;
            const uint2 u = bb4[i];
            const float e0 = __expf(s4[0][i] + bf2f((unsigned short)(u.x)));
            const float e1 = __expf(s4[1][i] + bf2f((unsigned short)(u.x >> 16)));
            const float e2 = __expf(s4[2][i] + bf2f((unsigned short)(u.y)));
            const float e3 = __expf(s4[3][i] + bf2f((unsigned short)(u.y >> 16)));
            float ssum = (e0 + e1) + (e2 + e3);
            #pragma unroll
            for (int o = 1; o < 16; o <<= 1) ssum += __shfl_xor(ssum, o);
            inv4[i] = 1.0f / ssum;
            const unsigned plo = pk2(e0, e1), phi = pk2(e2, e3);
            p_[n][     ln] = (unsigned short)plo;
            p_[n][16 + ln] = (unsigned short)(plo >> 16);
            p_[n][32 + ln] = (unsigned short)phi;
            p_[n][48 + ln] = (unsigned short)(phi >> 16);
        }

        // ---- prefetch next head's bias (hidden under PV + QKV + proj) ----
        {
            const int hn = (h < 5) ? h + 1 : 5;
            const unsigned short* bg = bias_g + (size_t)(wi * 6 + hn) * 3136;
            #pragma unroll
            for (int i = 0; i < 4; ++i) {
                const int nc = min(m0 + ro + i, 48);
                bb4[i] = *(const uint2*)(bg + nc * 64 + ln * 4);
            }
        }

        // ---- O = P @ V (unnormalized), scale by inv4 on store -> o_ ----
        f32x4 o2[2];
        o2[0] = f32x4{0.f,0.f,0.f,0.f}; o2[1] = f32x4{0.f,0.f,0.f,0.f};
        #pragma unroll
        for (int kf = 0; kf < 2; ++kf) {
            const s16x8 ap = *(const s16x8*)&p_[m0 + ln][kf * 32 + ko];
            #pragma unroll
            for (int nf = 0; nf < 2; ++nf) {
                const s16x8 bv = *(const s16x8*)&vt2_[h & 1][nf * 16 + ln][kf * 32 + ko];
                o2[nf] = __builtin_amdgcn_mfma_f32_16x16x32_bf16(ap, bv, o2[nf], 0, 0, 0);
            }
        }
        #pragma unroll
        for (int nf = 0; nf < 2; ++nf) {
            const int col = nf * 16 + ln;
            const unsigned lo = pk2(o2[nf][0] * inv4[0], o2[nf][1] * inv4[1]);
            const unsigned hh2 = pk2(o2[nf][2] * inv4[2], o2[nf][3] * inv4[3]);
            o_[m0+ro+0][col] = (unsigned short)lo;  o_[m0+ro+1][col] = (unsigned short)(lo >> 16);
            o_[m0+ro+2][col] = (unsigned short)hh2; o_[m0+ro+3][col] = (unsigned short)(hh2 >> 16);
        }

        // ---- QKV for next head into other buffer (overlaps this head's tail) ----
        if (h < 5) qkv_head(h + 1);

        // ---- proj partial: all 12 fragments batched (o_ wave-private) ----
        {
            const s16x8 ao = *(const s16x8*)&o_[m0 + ln][ko];
            const s16x8* wpj = wv + ((size_t)(216 + h * 12) << 6);
            s16x8 bf12[12];
            #pragma unroll
            for (int nf = 0; nf < 12; ++nf) bf12[nf] = wpj[nf * 64 + lane];
            #pragma unroll
            for (int nf = 0; nf < 12; ++nf)
                accp[nf] = __builtin_amdgcn_mfma_f32_16x16x32_bf16(
                    ao, bf12[nf], accp[nf], 0, 0, 0);
        }
    }

    // ---- Epilogue: + proj bias + residual, scatter to shifted coords ----
    #pragma unroll
    for (int i = 0; i < 4; ++i) {
        const int n = m0 + ro + i;
        if (n < 49) {
            const int p = n / 7, q7 = n - p * 7;
            int i2 = wh * 7 + p + 3;  if (i2 >= 56) i2 -= 56;
            int j2 = ww * 7 + q7 + 3; if (j2 >= 56) j2 -= 56;
            const size_t base = ((size_t)(bb * 56 + i2) * 56 + j2) * 192;
            #pragma unroll
            for (int nf = 0; nf < 12; ++nf) {
                const int col = nf * 16 + ln;
                y[base + col] = x[base + col] + pb[col] + accp[nf][i];
            }
        }
    }
}

// stage one 24 KB chunk (fc1_c 12K + fc2_c 12K) into LDS with 256 threads, async (6 GLDS/thread)
__device__ __forceinline__ void stage24k(const unsigned short* __restrict__ wp, int c,
                                         unsigned short* dst, int tid) {
    const unsigned short* g = wp + (((size_t)(288 + c * 24)) << 9) + tid * 8;
    unsigned short* l = dst + tid * 8;
    #pragma unroll
    for (int i = 0; i < 6; ++i)
        GLDS16(g + i * 2048, l + i * 2048);
}

// ===== Kernel B: LN2 + fc1 + GELU + fc2 + residual; 32 rows/wave =====
__global__ __launch_bounds__(256, 2)
void swin_mlp(const float* __restrict__ g2, const float* __restrict__ b2,
              const unsigned short* __restrict__ wp,
              const float* __restrict__ f1b, const float* __restrict__ f2b,
              float* __restrict__ y)
{
    __shared__ __align__(16) unsigned short wbuf[2][12288]; // 49152 B (fc1|fc2 chunk, dbuf)
    __shared__ __align__(16) unsigned short hb[128][40];    // 10240 B (rows wave-private)
    __shared__ float f1b_l[768];                            // 3072 B
    __shared__ float f2b_l[192];                            // 768 B

    const int tid = threadIdx.x, lane = tid & 63, wave = tid >> 6;
    const int ln = lane & 15, hi = lane >> 4, ko = hi * 8, ro = hi * 4;
    const int m0 = wave * 32;                    // 0,32,64,96
    const size_t r0 = (size_t)blockIdx.x * 128;

    for (int t = tid; t < 768; t += 256) f1b_l[t] = f1b[t];
    for (int t = tid; t < 192; t += 256) f2b_l[t] = f2b[t];

    s16x8 xa[12];
    ln_frag(y + (r0 + m0 +      ln) * 192, g2, b2, hi, xa);
    ln_frag(y + (r0 + m0 + 16 + ln) * 192, g2, b2, hi, xa + 6);

    stage24k(wp, 0, wbuf[0], tid);
    stage24k(wp, 1, wbuf[1], tid);
    asm volatile("s_waitcnt lgkmcnt(0)" ::: "memory");

    f32x4 acc2[24];
    #pragma unroll
    for (int i = 0; i < 24; ++i) acc2[i] = f32x4{0.f,0.f,0.f,0.f};

    for (int c = 0; c < 24; ++c) {
        if (c == 23) asm volatile("s_waitcnt vmcnt(0)" ::: "memory");
        else         asm volatile("s_waitcnt vmcnt(6)" ::: "memory");
        __builtin_amdgcn_s_barrier();

        const s16x8* wb = (const s16x8*)wbuf[c & 1];
        f32x4 acc1[4];
        #pragma unroll
        for (int i = 0; i < 4; ++i) acc1[i] = f32x4{0.f,0.f,0.f,0.f};
        #pragma unroll
        for (int kf = 0; kf < 6; ++kf) {
            #pragma unroll
            for (int nf = 0; nf < 2; ++nf) {
                const s16x8 b = wb[(nf * 6 + kf) * 64 + lane];
                acc1[nf*2+0] = __builtin_amdgcn_mfma_f32_16x16x32_bf16(xa[kf],     b, acc1[nf*2+0], 0, 0, 0);
                acc1[nf*2+1] = __builtin_amdgcn_mfma_f32_16x16x32_bf16(xa[6 + kf], b, acc1[nf*2+1], 0, 0, 0);
            }
        }
        #pragma unroll
        for (int nf = 0; nf < 2; ++nf) {
            const int col = nf * 16 + ln;
            const float bias = f1b_l[c * 32 + col];
            #pragma unroll
            for (int rs = 0; rs < 2; ++rs) {
                const f32x4 a = acc1[nf*2+rs];
                const int rb = m0 + rs * 16 + ro;
                const unsigned lo = pk2(gelu_f(a[0] + bias), gelu_f(a[1] + bias));
                const unsigned hh2 = pk2(gelu_f(a[2] + bias), gelu_f(a[3] + bias));
                hb[rb+0][col] = (unsigned short)lo;  hb[rb+1][col] = (unsigned short)(lo >> 16);
                hb[rb+2][col] = (unsigned short)hh2; hb[rb+3][col] = (unsigned short)(hh2 >> 16);
            }
        }
        const s16x8 ah0 = *(const s16x8*)&hb[m0 +      ln][ko];
        const s16x8 ah1 = *(const s16x8*)&hb[m0 + 16 + ln][ko];
        #pragma unroll
        for (int nf = 0; nf < 12; ++nf) {
            const s16x8 b = wb[(12 + nf) * 64 + lane];
            acc2[nf*2+0] = __builtin_amdgcn_mfma_f32_16x16x32_bf16(ah0, b, acc2[nf*2+0], 0, 0, 0);
            acc2[nf*2+1] = __builtin_amdgcn_mfma_f32_16x16x32_bf16(ah1, b, acc2[nf*2+1], 0, 0, 0);
        }

        if (c < 23) {
            __builtin_amdgcn_s_barrier();
            if (c < 22) stage24k(wp, c + 2, wbuf[c & 1], tid);
        }
    }

    #pragma unroll
    for (int rs = 0; rs < 2; ++rs) {
        #pragma unroll
        for (int i = 0; i < 4; ++i) {
            const int row = m0 + rs * 16 + ro + i;
            float* yp = y + (r0 + row) * 192;
            #pragma unroll
            for (int nf = 0; nf < 12; ++nf) {
                const int col = nf * 16 + ln;
                yp[col] = yp[col] + f2b_l[col] + acc2[nf*2+rs][i];
            }
        }
    }
}

extern "C" void kernel_launch(void* const* d_in, const int* in_sizes, int n_in,
                              void* d_out, int out_size, void* d_ws, size_t ws_size,
                              hipStream_t stream) {
    (void)in_sizes; (void)n_in; (void)ws_size; (void)out_size;
    const float* x    = (const float*)d_in[0];
    const float* mask = (const float*)d_in[1];
    const float* g1   = (const float*)d_in[2];
    const float* b1   = (const float*)d_in[3];
    const float* qkvw = (const float*)d_in[4];
    const float* qkvb = (const float*)d_in[5];
    const float* rpb  = (const float*)d_in[6];
    const float* pw   = (const float*)d_in[7];
    const float* pb   = (const float*)d_in[8];
    const float* g2   = (const float*)d_in[9];
    const float* b2   = (const float*)d_in[10];
    const float* f1w  = (const float*)d_in[11];
    const float* f1b  = (const float*)d_in[12];
    const float* f2w  = (const float*)d_in[13];
    const float* f2b  = (const float*)d_in[14];
    float* y = (float*)d_out;
    unsigned short* wpk  = (unsigned short*)d_ws;   // 884,736 B
    unsigned short* bias = wpk + 442368;            // 2,408,448 B -> ~3.3 MB total

    pack_all<<<dim3(600), dim3(256), 0, stream>>>(qkvw, pw, f1w, f2w, mask, rpb, wpk, bias);
    swin_attn<<<dim3(64 * 64), dim3(256), 0, stream>>>(
        x, g1, b1, wpk, bias, qkvb, pb, y);
    swin_mlp<<<dim3(1568), dim3(256), 0, stream>>>(
        g2, b2, wpk, f1b, f2b, y);
}

// Round 15
// 614.897 us; speedup vs baseline: 1.1016x; 1.1016x over previous
//
#include <hip/hip_runtime.h>
#include <hip/hip_bf16.h>
#include <math.h>

typedef __attribute__((ext_vector_type(8))) short s16x8;
typedef __attribute__((ext_vector_type(4))) float f32x4;

static constexpr float cSCALE = 0.17677669529663687f; // 32^-0.5

__device__ __forceinline__ float bf2f(unsigned short u) {
    union { unsigned int i; float f; } c; c.i = ((unsigned int)u) << 16; return c.f;
}
__device__ __forceinline__ unsigned short f2bf(float f) {
    union { float f; unsigned int i; } c; c.f = f;
    unsigned int r = c.i + (0x7fffu + ((c.i >> 16) & 1u));
    return (unsigned short)(r >> 16);
}
// HW packed f32->bf16 (RNE): lo = a, hi = b
__device__ __forceinline__ unsigned pk2(float a, float b) {
    unsigned r;
    asm("v_cvt_pk_bf16_f32 %0, %1, %2" : "=v"(r) : "v"(a), "v"(b));
    return r;
}
__device__ __forceinline__ s16x8 cvt8(const float4 a, const float4 b) {
    s16x8 r;
    r[0]=(short)f2bf(a.x); r[1]=(short)f2bf(a.y); r[2]=(short)f2bf(a.z); r[3]=(short)f2bf(a.w);
    r[4]=(short)f2bf(b.x); r[5]=(short)f2bf(b.y); r[6]=(short)f2bf(b.z); r[7]=(short)f2bf(b.w);
    return r;
}
__device__ __forceinline__ float gelu_f(float t) {
    const float u = 1.5957691216057308f * t * (1.0f + 0.044715f * t * t);
    return t / (1.0f + __expf(-u));
}

#define GLDS16(gp, lp) __builtin_amdgcn_global_load_lds( \
    (const __attribute__((address_space(1))) void*)(gp), \
    (__attribute__((address_space(3))) void*)(lp), 16, 0, 0)

// In-register LayerNorm of one 192-col row -> 6 MFMA A-fragments (cvt_pk packed).
__device__ __forceinline__ void ln_frag(const float* __restrict__ rowp,
                                        const float* __restrict__ g,
                                        const float* __restrict__ b,
                                        int hi, s16x8* xa)
{
    float4 v[12];
    #pragma unroll
    for (int k = 0; k < 6; ++k) {
        v[2*k]   = *(const float4*)(rowp + k*32 + hi*8);
        v[2*k+1] = *(const float4*)(rowp + k*32 + hi*8 + 4);
    }
    float sm = 0.f, sq = 0.f;
    #pragma unroll
    for (int i = 0; i < 12; ++i) {
        sm += (v[i].x + v[i].y) + (v[i].z + v[i].w);
        sq += (v[i].x*v[i].x + v[i].y*v[i].y) + (v[i].z*v[i].z + v[i].w*v[i].w);
    }
    sm += __shfl_xor(sm, 16); sq += __shfl_xor(sq, 16);
    sm += __shfl_xor(sm, 32); sq += __shfl_xor(sq, 32);
    const float mean = sm * (1.0f/192.0f);
    const float rstd = rsqrtf(sq * (1.0f/192.0f) - mean*mean + 1e-5f);
    #pragma unroll
    for (int k = 0; k < 6; ++k) {
        const float4 ga = *(const float4*)(g + k*32 + hi*8);
        const float4 gb = *(const float4*)(g + k*32 + hi*8 + 4);
        const float4 ba = *(const float4*)(b + k*32 + hi*8);
        const float4 bb = *(const float4*)(b + k*32 + hi*8 + 4);
        union { s16x8 s; unsigned u[4]; } r;
        r.u[0] = pk2((v[2*k].x  -mean)*rstd*ga.x + ba.x, (v[2*k].y  -mean)*rstd*ga.y + ba.y);
        r.u[1] = pk2((v[2*k].z  -mean)*rstd*ga.z + ba.z, (v[2*k].w  -mean)*rstd*ga.w + ba.w);
        r.u[2] = pk2((v[2*k+1].x-mean)*rstd*gb.x + bb.x, (v[2*k+1].y-mean)*rstd*gb.y + bb.y);
        r.u[3] = pk2((v[2*k+1].z-mean)*rstd*gb.z + bb.z, (v[2*k+1].w-mean)*rstd*gb.w + bb.w);
        xa[k] = r.s;
    }
}

// ============ Prep (merged): pack weights + fold rpb/mask bias into d_ws ============
__global__ __launch_bounds__(256)
void pack_all(const float* __restrict__ qkvw, const float* __restrict__ pw,
              const float* __restrict__ f1w, const float* __restrict__ f2w,
              const float* __restrict__ mask, const float* __restrict__ rpb,
              unsigned short* __restrict__ o, unsigned short* __restrict__ ob)
{
    if (blockIdx.x < 216) {
        const int t = blockIdx.x * 256 + threadIdx.x; // 0..55295
        const int lane = t & 63, f = t >> 6;
        const int ln = lane & 15, ko = (lane >> 4) * 8;
        const float* src;
        if (f < 216) {
            const int h = f / 36, r = f - h * 36, nf = r / 6, kf = r - nf * 6;
            src = qkvw + (size_t)((nf >> 1) * 192 + h * 32 + (nf & 1) * 16 + ln) * 192 + kf * 32 + ko;
        } else if (f < 288) {
            const int g = f - 216, h = g / 12, nf = g - h * 12;
            src = pw + (size_t)(nf * 16 + ln) * 192 + h * 32 + ko;
        } else {
            const int g = f - 288;
            const int c = g / 24, r24 = g - c * 24;
            if (r24 < 12) {
                const int nf = r24 / 6, kf = r24 - nf * 6;
                src = f1w + (size_t)(c * 32 + nf * 16 + ln) * 192 + kf * 32 + ko;
            } else {
                const int nf = r24 - 12;
                src = f2w + (size_t)(nf * 16 + ln) * 768 + c * 32 + ko;
            }
        }
        *(s16x8*)(o + (size_t)t * 8) = cvt8(*(const float4*)src, *(const float4*)(src + 4));
    } else {
        const int bid = blockIdx.x - 216;            // 0..383
        const int wi = bid / 6, h = bid - wi * 6;
        for (int t = threadIdx.x; t < 49 * 64; t += 256) {
            const int n = t >> 6, mm = t & 63;
            const int ln = mm >> 2, nf = mm & 3;
            const int m = nf * 16 + ln;
            float v = -100.0f;
            if (m < 49) {
                const int p1 = n / 7, q1 = n - p1 * 7, p2 = m / 7, q2 = m - p2 * 7;
                const int ridx = (p1 - p2 + 6) * 13 + (q1 - q2 + 6);
                v = rpb[ridx * 6 + h] + mask[(size_t)wi * 2401 + n * 49 + m];
            }
            ob[(size_t)(wi * 6 + h) * 3136 + t] = f2bf(v);
        }
    }
}

// ============ Kernel A: LN1 + shift/window + MFMA attention + proj + residual ============
__global__ __launch_bounds__(256, 3)
void swin_attn(const float* __restrict__ x, const float* __restrict__ g1,
               const float* __restrict__ b1, const unsigned short* __restrict__ wp,
               const unsigned short* __restrict__ bias_g,
               const float* __restrict__ qkvb, const float* __restrict__ pb,
               float* __restrict__ y)
{
    __shared__ __align__(16) unsigned short q_[64][40];      // 5120 (wave-private rows)
    __shared__ __align__(16) unsigned short o_[64][40];      // 5120 (wave-private rows)
    __shared__ __align__(16) unsigned short k2_[2][64][40];  // 10240 (cross-wave, dbuf)
    __shared__ __align__(16) unsigned short vt2_[2][32][72]; // 9216 (cross-wave, dbuf)
    __shared__ __align__(16) unsigned short p_[64][72];      // 9216 (wave-private rows)
    // total 38912 B -> 3 blocks/CU at (256,3)

    const s16x8* wv = (const s16x8*)wp;
    const int w  = blockIdx.x;
    const int bb = w >> 6, wi = w & 63;
    const int wh = wi >> 3, ww = wi & 7;
    const int tid = threadIdx.x, lane = tid & 63, wave = tid >> 6;
    const int ln = lane & 15, hi = lane >> 4, ko = hi * 8, ro = hi * 4;
    const int m0 = wave * 16;

    // ---- LN1 fully in registers ----
    s16x8 xa[6];
    {
        const int t = m0 + ln;
        const int p = t / 7, q7 = t - p * 7;
        int i2 = wh * 7 + p + 3;  if (i2 >= 56) i2 -= 56;
        int j2 = ww * 7 + q7 + 3; if (j2 >= 56) j2 -= 56;
        const float* xr = x + ((size_t)(bb * 56 + i2) * 56 + j2) * 192;
        ln_frag(xr, g1, b1, hi, xa);
        if (t >= 49) {
            #pragma unroll
            for (int k = 0; k < 6; ++k) xa[k] = s16x8{0,0,0,0,0,0,0,0};
        }
    }

    // per-output store of one QKV nf column-group (nf compile-time constant at expansion)
    auto store_qkv = [&](int hh, int nf, f32x4 a) {
        const int col = nf * 16 + ln;
        if (nf < 2) {
            const float bq = qkvb[hh*32 + col];
            const unsigned lo = pk2((a[0]+bq)*cSCALE, (a[1]+bq)*cSCALE);
            const unsigned hh2 = pk2((a[2]+bq)*cSCALE, (a[3]+bq)*cSCALE);
            q_[m0+ro+0][col] = (unsigned short)lo;  q_[m0+ro+1][col] = (unsigned short)(lo >> 16);
            q_[m0+ro+2][col] = (unsigned short)hh2; q_[m0+ro+3][col] = (unsigned short)(hh2 >> 16);
        } else if (nf < 4) {
            const float bk = qkvb[192 + hh*32 + col - 32];
            const unsigned lo = pk2(a[0]+bk, a[1]+bk), hh2 = pk2(a[2]+bk, a[3]+bk);
            k2_[hh&1][m0+ro+0][col-32] = (unsigned short)lo;  k2_[hh&1][m0+ro+1][col-32] = (unsigned short)(lo >> 16);
            k2_[hh&1][m0+ro+2][col-32] = (unsigned short)hh2; k2_[hh&1][m0+ro+3][col-32] = (unsigned short)(hh2 >> 16);
        } else {
            const float bv = qkvb[384 + hh*32 + col - 64];
            const unsigned lo = pk2(a[0]+bv, a[1]+bv), hh2 = pk2(a[2]+bv, a[3]+bv);
            vt2_[hh&1][col-64][m0+ro+0] = (unsigned short)lo;  vt2_[hh&1][col-64][m0+ro+1] = (unsigned short)(lo >> 16);
            vt2_[hh&1][col-64][m0+ro+2] = (unsigned short)hh2; vt2_[hh&1][col-64][m0+ro+3] = (unsigned short)(hh2 >> 16);
        }
    };

// 2-deep software-pipelined QKV: named arrays, constant indices only (no pointer select)
#define QKV_LOAD(ARR, NF) { \
    _Pragma("unroll") \
    for (int kf_ = 0; kf_ < 6; ++kf_) ARR[kf_] = wq[((NF) * 6 + kf_) * 64 + lane]; }
#define QKV_STEP(NF, ARR) { \
    f32x4 a_ = f32x4{0.f,0.f,0.f,0.f}; \
    _Pragma("unroll") \
    for (int kf_ = 0; kf_ < 6; ++kf_) \
        a_ = __builtin_amdgcn_mfma_f32_16x16x32_bf16(xa[kf_], ARR[kf_], a_, 0, 0, 0); \
    store_qkv(hh, (NF), a_); }

    auto qkv_head = [&](int hh) {
        const s16x8* wq = wv + ((size_t)(hh * 36) << 6);
        s16x8 pA[6], pB[6];
        QKV_LOAD(pA, 0)
        QKV_LOAD(pB, 1)
        QKV_STEP(0, pA)
        QKV_LOAD(pA, 2)
        QKV_STEP(1, pB)
        QKV_LOAD(pB, 3)
        QKV_STEP(2, pA)
        QKV_LOAD(pA, 4)
        QKV_STEP(3, pB)
        QKV_LOAD(pB, 5)
        QKV_STEP(4, pA)
        QKV_STEP(5, pB)
    };

    qkv_head(0);

    f32x4 accp[12];
    #pragma unroll
    for (int i = 0; i < 12; ++i) accp[i] = f32x4{0.f,0.f,0.f,0.f};

    // bias prefetch for head 0 (clamped rows; garbage rows discarded at epilogue)
    uint2 bb4[4];
    {
        const unsigned short* bg = bias_g + (size_t)(wi * 6) * 3136;
        #pragma unroll
        for (int i = 0; i < 4; ++i) {
            const int nc = min(m0 + ro + i, 48);
            bb4[i] = *(const uint2*)(bg + nc * 64 + ln * 4);
        }
    }

    for (int h = 0; h < 6; ++h) {
        __syncthreads();   // k2_/vt2_[h&1] visible to all waves

        // ---- S = Q @ K^T + fused bias (mask baked); softmax without max-reduce ----
        f32x4 s4[4];
        {
            const s16x8 aq = *(const s16x8*)&q_[m0 + ln][ko];
            #pragma unroll
            for (int nf = 0; nf < 4; ++nf) {
                const s16x8 bk = *(const s16x8*)&k2_[h & 1][nf * 16 + ln][ko];
                s4[nf] = __builtin_amdgcn_mfma_f32_16x16x32_bf16(aq, bk, f32x4{0.f,0.f,0.f,0.f}, 0, 0, 0);
            }
        }
        float inv4[4];
        #pragma unroll
        for (int i = 0; i < 4; ++i) {
            const int n = m0 + ro + i;
            const uint2 u = bb4[i];
            const float e0 = __expf(s4[0][i] + bf2f((unsigned short)(u.x)));
            const float e1 = __expf(s4[1][i] + bf2f((unsigned short)(u.x >> 16)));
            const float e2 = __expf(s4[2][i] + bf2f((unsigned short)(u.y)));
            const float e3 = __expf(s4[3][i] + bf2f((unsigned short)(u.y >> 16)));
            float ssum = (e0 + e1) + (e2 + e3);
            #pragma unroll
            for (int o = 1; o < 16; o <<= 1) ssum += __shfl_xor(ssum, o);
            inv4[i] = 1.0f / ssum;
            const unsigned plo = pk2(e0, e1), phi = pk2(e2, e3);
            p_[n][     ln] = (unsigned short)plo;
            p_[n][16 + ln] = (unsigned short)(plo >> 16);
            p_[n][32 + ln] = (unsigned short)phi;
            p_[n][48 + ln] = (unsigned short)(phi >> 16);
        }

        // ---- prefetch next head's bias (hidden under PV + QKV + proj) ----
        {
            const int hn = (h < 5) ? h + 1 : 5;
            const unsigned short* bg = bias_g + (size_t)(wi * 6 + hn) * 3136;
            #pragma unroll
            for (int i = 0; i < 4; ++i) {
                const int nc = min(m0 + ro + i, 48);
                bb4[i] = *(const uint2*)(bg + nc * 64 + ln * 4);
            }
        }

        // ---- O = P @ V (unnormalized), scale by inv4 on store -> o_ ----
        f32x4 o2[2];
        o2[0] = f32x4{0.f,0.f,0.f,0.f}; o2[1] = f32x4{0.f,0.f,0.f,0.f};
        #pragma unroll
        for (int kf = 0; kf < 2; ++kf) {
            const s16x8 ap = *(const s16x8*)&p_[m0 + ln][kf * 32 + ko];
            #pragma unroll
            for (int nf = 0; nf < 2; ++nf) {
                const s16x8 bv = *(const s16x8*)&vt2_[h & 1][nf * 16 + ln][kf * 32 + ko];
                o2[nf] = __builtin_amdgcn_mfma_f32_16x16x32_bf16(ap, bv, o2[nf], 0, 0, 0);
            }
        }
        #pragma unroll
        for (int nf = 0; nf < 2; ++nf) {
            const int col = nf * 16 + ln;
            const unsigned lo = pk2(o2[nf][0] * inv4[0], o2[nf][1] * inv4[1]);
            const unsigned hh2 = pk2(o2[nf][2] * inv4[2], o2[nf][3] * inv4[3]);
            o_[m0+ro+0][col] = (unsigned short)lo;  o_[m0+ro+1][col] = (unsigned short)(lo >> 16);
            o_[m0+ro+2][col] = (unsigned short)hh2; o_[m0+ro+3][col] = (unsigned short)(hh2 >> 16);
        }

        // ---- QKV for next head into other buffer (overlaps this head's tail) ----
        if (h < 5) qkv_head(h + 1);

        // ---- proj partial: 12 fragments in two named batches, loads front-loaded ----
        {
            const s16x8 ao = *(const s16x8*)&o_[m0 + ln][ko];
            const s16x8* wpj = wv + ((size_t)(216 + h * 12) << 6);
            s16x8 jA[6], jB[6];
            #pragma unroll
            for (int nf = 0; nf < 6; ++nf) jA[nf] = wpj[nf * 64 + lane];
            #pragma unroll
            for (int nf = 0; nf < 6; ++nf) jB[nf] = wpj[(6 + nf) * 64 + lane];
            #pragma unroll
            for (int nf = 0; nf < 6; ++nf)
                accp[nf] = __builtin_amdgcn_mfma_f32_16x16x32_bf16(ao, jA[nf], accp[nf], 0, 0, 0);
            #pragma unroll
            for (int nf = 0; nf < 6; ++nf)
                accp[6 + nf] = __builtin_amdgcn_mfma_f32_16x16x32_bf16(ao, jB[nf], accp[6 + nf], 0, 0, 0);
        }
    }

    // ---- Epilogue: + proj bias + residual, scatter to shifted coords ----
    #pragma unroll
    for (int i = 0; i < 4; ++i) {
        const int n = m0 + ro + i;
        if (n < 49) {
            const int p = n / 7, q7 = n - p * 7;
            int i2 = wh * 7 + p + 3;  if (i2 >= 56) i2 -= 56;
            int j2 = ww * 7 + q7 + 3; if (j2 >= 56) j2 -= 56;
            const size_t base = ((size_t)(bb * 56 + i2) * 56 + j2) * 192;
            #pragma unroll
            for (int nf = 0; nf < 12; ++nf) {
                const int col = nf * 16 + ln;
                y[base + col] = x[base + col] + pb[col] + accp[nf][i];
            }
        }
    }
}

// stage one 24 KB chunk (fc1_c 12K + fc2_c 12K) into LDS with 256 threads, async (6 GLDS/thread)
__device__ __forceinline__ void stage24k(const unsigned short* __restrict__ wp, int c,
                                         unsigned short* dst, int tid) {
    const unsigned short* g = wp + (((size_t)(288 + c * 24)) << 9) + tid * 8;
    unsigned short* l = dst + tid * 8;
    #pragma unroll
    for (int i = 0; i < 6; ++i)
        GLDS16(g + i * 2048, l + i * 2048);
}

// ===== Kernel B: LN2 + fc1 + GELU + fc2 + residual; 32 rows/wave =====
__global__ __launch_bounds__(256, 2)
void swin_mlp(const float* __restrict__ g2, const float* __restrict__ b2,
              const unsigned short* __restrict__ wp,
              const float* __restrict__ f1b, const float* __restrict__ f2b,
              float* __restrict__ y)
{
    __shared__ __align__(16) unsigned short wbuf[2][12288]; // 49152 B (fc1|fc2 chunk, dbuf)
    __shared__ __align__(16) unsigned short hb[128][40];    // 10240 B (rows wave-private)
    __shared__ float f1b_l[768];                            // 3072 B
    __shared__ float f2b_l[192];                            // 768 B

    const int tid = threadIdx.x, lane = tid & 63, wave = tid >> 6;
    const int ln = lane & 15, hi = lane >> 4, ko = hi * 8, ro = hi * 4;
    const int m0 = wave * 32;                    // 0,32,64,96
    const size_t r0 = (size_t)blockIdx.x * 128;

    for (int t = tid; t < 768; t += 256) f1b_l[t] = f1b[t];
    for (int t = tid; t < 192; t += 256) f2b_l[t] = f2b[t];

    s16x8 xa[12];
    ln_frag(y + (r0 + m0 +      ln) * 192, g2, b2, hi, xa);
    ln_frag(y + (r0 + m0 + 16 + ln) * 192, g2, b2, hi, xa + 6);

    stage24k(wp, 0, wbuf[0], tid);
    stage24k(wp, 1, wbuf[1], tid);
    asm volatile("s_waitcnt lgkmcnt(0)" ::: "memory");

    f32x4 acc2[24];
    #pragma unroll
    for (int i = 0; i < 24; ++i) acc2[i] = f32x4{0.f,0.f,0.f,0.f};

    for (int c = 0; c < 24; ++c) {
        if (c == 23) asm volatile("s_waitcnt vmcnt(0)" ::: "memory");
        else         asm volatile("s_waitcnt vmcnt(6)" ::: "memory");
        __builtin_amdgcn_s_barrier();

        const s16x8* wb = (const s16x8*)wbuf[c & 1];
        f32x4 acc1[4];
        #pragma unroll
        for (int i = 0; i < 4; ++i) acc1[i] = f32x4{0.f,0.f,0.f,0.f};
        #pragma unroll
        for (int kf = 0; kf < 6; ++kf) {
            #pragma unroll
            for (int nf = 0; nf < 2; ++nf) {
                const s16x8 b = wb[(nf * 6 + kf) * 64 + lane];
                acc1[nf*2+0] = __builtin_amdgcn_mfma_f32_16x16x32_bf16(xa[kf],     b, acc1[nf*2+0], 0, 0, 0);
                acc1[nf*2+1] = __builtin_amdgcn_mfma_f32_16x16x32_bf16(xa[6 + kf], b, acc1[nf*2+1], 0, 0, 0);
            }
        }
        #pragma unroll
        for (int nf = 0; nf < 2; ++nf) {
            const int col = nf * 16 + ln;
            const float bias = f1b_l[c * 32 + col];
            #pragma unroll
            for (int rs = 0; rs < 2; ++rs) {
                const f32x4 a = acc1[nf*2+rs];
                const int rb = m0 + rs * 16 + ro;
                const unsigned lo = pk2(gelu_f(a[0] + bias), gelu_f(a[1] + bias));
                const unsigned hh2 = pk2(gelu_f(a[2] + bias), gelu_f(a[3] + bias));
                hb[rb+0][col] = (unsigned short)lo;  hb[rb+1][col] = (unsigned short)(lo >> 16);
                hb[rb+2][col] = (unsigned short)hh2; hb[rb+3][col] = (unsigned short)(hh2 >> 16);
            }
        }
        const s16x8 ah0 = *(const s16x8*)&hb[m0 +      ln][ko];
        const s16x8 ah1 = *(const s16x8*)&hb[m0 + 16 + ln][ko];
        #pragma unroll
        for (int nf = 0; nf < 12; ++nf) {
            const s16x8 b = wb[(12 + nf) * 64 + lane];
            acc2[nf*2+0] = __builtin_amdgcn_mfma_f32_16x16x32_bf16(ah0, b, acc2[nf*2+0], 0, 0, 0);
            acc2[nf*2+1] = __builtin_amdgcn_mfma_f32_16x16x32_bf16(ah1, b, acc2[nf*2+1], 0, 0, 0);
        }

        if (c < 23) {
            __builtin_amdgcn_s_barrier();
            if (c < 22) stage24k(wp, c + 2, wbuf[c & 1], tid);
        }
    }

    #pragma unroll
    for (int rs = 0; rs < 2; ++rs) {
        #pragma unroll
        for (int i = 0; i < 4; ++i) {
            const int row = m0 + rs * 16 + ro + i;
            float* yp = y + (r0 + row) * 192;
            #pragma unroll
            for (int nf = 0; nf < 12; ++nf) {
                const int col = nf * 16 + ln;
                yp[col] = yp[col] + f2b_l[col] + acc2[nf*2+rs][i];
            }
        }
    }
}

extern "C" void kernel_launch(void* const* d_in, const int* in_sizes, int n_in,
                              void* d_out, int out_size, void* d_ws, size_t ws_size,
                              hipStream_t stream) {
    (void)in_sizes; (void)n_in; (void)ws_size; (void)out_size;
    const float* x    = (const float*)d_in[0];
    const float* mask = (const float*)d_in[1];
    const float* g1   = (const float*)d_in[2];
    const float* b1   = (const float*)d_in[3];
    const float* qkvw = (const float*)d_in[4];
    const float* qkvb = (const float*)d_in[5];
    const float* rpb  = (const float*)d_in[6];
    const float* pw   = (const float*)d_in[7];
    const float* pb   = (const float*)d_in[8];
    const float* g2   = (const float*)d_in[9];
    const float* b2   = (const float*)d_in[10];
    const float* f1w  = (const float*)d_in[11];
    const float* f1b  = (const float*)d_in[12];
    const float* f2w  = (const float*)d_in[13];
    const float* f2b  = (const float*)d_in[14];
    float* y = (float*)d_out;
    unsigned short* wpk  = (unsigned short*)d_ws;   // 884,736 B
    unsigned short* bias = wpk + 442368;            // 2,408,448 B -> ~3.3 MB total

    pack_all<<<dim3(600), dim3(256), 0, stream>>>(qkvw, pw, f1w, f2w, mask, rpb, wpk, bias);
    swin_attn<<<dim3(64 * 64), dim3(256), 0, stream>>>(
        x, g1, b1, wpk, bias, qkvb, pb, y);
    swin_mlp<<<dim3(1568), dim3(256), 0, stream>>>(
        g2, b2, wpk, f1b, f2b, y);
}

// Round 16
// 479.609 us; speedup vs baseline: 1.4123x; 1.2821x over previous
//
#include <hip/hip_runtime.h>
#include <hip/hip_bf16.h>
#include <math.h>

typedef __attribute__((ext_vector_type(8))) short s16x8;
typedef __attribute__((ext_vector_type(4))) float f32x4;

static constexpr float cSCALE = 0.17677669529663687f; // 32^-0.5

__device__ __forceinline__ float bf2f(unsigned short u) {
    union { unsigned int i; float f; } c; c.i = ((unsigned int)u) << 16; return c.f;
}
__device__ __forceinline__ unsigned short f2bf(float f) {
    union { float f; unsigned int i; } c; c.f = f;
    unsigned int r = c.i + (0x7fffu + ((c.i >> 16) & 1u));
    return (unsigned short)(r >> 16);
}
// HW packed f32->bf16 (RNE): lo = a, hi = b
__device__ __forceinline__ unsigned pk2(float a, float b) {
    unsigned r;
    asm("v_cvt_pk_bf16_f32 %0, %1, %2" : "=v"(r) : "v"(a), "v"(b));
    return r;
}
__device__ __forceinline__ s16x8 cvt8(const float4 a, const float4 b) {
    s16x8 r;
    r[0]=(short)f2bf(a.x); r[1]=(short)f2bf(a.y); r[2]=(short)f2bf(a.z); r[3]=(short)f2bf(a.w);
    r[4]=(short)f2bf(b.x); r[5]=(short)f2bf(b.y); r[6]=(short)f2bf(b.z); r[7]=(short)f2bf(b.w);
    return r;
}
__device__ __forceinline__ float gelu_f(float t) {
    const float u = 1.5957691216057308f * t * (1.0f + 0.044715f * t * t);
    return t / (1.0f + __expf(-u));
}

#define GLDS16(gp, lp) __builtin_amdgcn_global_load_lds( \
    (const __attribute__((address_space(1))) void*)(gp), \
    (__attribute__((address_space(3))) void*)(lp), 16, 0, 0)

// In-register LayerNorm of one 192-col row -> 6 MFMA A-fragments (cvt_pk packed).
__device__ __forceinline__ void ln_frag(const float* __restrict__ rowp,
                                        const float* __restrict__ g,
                                        const float* __restrict__ b,
                                        int hi, s16x8* xa)
{
    float4 v[12];
    #pragma unroll
    for (int k = 0; k < 6; ++k) {
        v[2*k]   = *(const float4*)(rowp + k*32 + hi*8);
        v[2*k+1] = *(const float4*)(rowp + k*32 + hi*8 + 4);
    }
    float sm = 0.f, sq = 0.f;
    #pragma unroll
    for (int i = 0; i < 12; ++i) {
        sm += (v[i].x + v[i].y) + (v[i].z + v[i].w);
        sq += (v[i].x*v[i].x + v[i].y*v[i].y) + (v[i].z*v[i].z + v[i].w*v[i].w);
    }
    sm += __shfl_xor(sm, 16); sq += __shfl_xor(sq, 16);
    sm += __shfl_xor(sm, 32); sq += __shfl_xor(sq, 32);
    const float mean = sm * (1.0f/192.0f);
    const float rstd = rsqrtf(sq * (1.0f/192.0f) - mean*mean + 1e-5f);
    #pragma unroll
    for (int k = 0; k < 6; ++k) {
        const float4 ga = *(const float4*)(g + k*32 + hi*8);
        const float4 gb = *(const float4*)(g + k*32 + hi*8 + 4);
        const float4 ba = *(const float4*)(b + k*32 + hi*8);
        const float4 bb = *(const float4*)(b + k*32 + hi*8 + 4);
        union { s16x8 s; unsigned u[4]; } r;
        r.u[0] = pk2((v[2*k].x  -mean)*rstd*ga.x + ba.x, (v[2*k].y  -mean)*rstd*ga.y + ba.y);
        r.u[1] = pk2((v[2*k].z  -mean)*rstd*ga.z + ba.z, (v[2*k].w  -mean)*rstd*ga.w + ba.w);
        r.u[2] = pk2((v[2*k+1].x-mean)*rstd*gb.x + bb.x, (v[2*k+1].y-mean)*rstd*gb.y + bb.y);
        r.u[3] = pk2((v[2*k+1].z-mean)*rstd*gb.z + bb.z, (v[2*k+1].w-mean)*rstd*gb.w + bb.w);
        xa[k] = r.s;
    }
}

// ============ Prep (merged): pack weights + fold rpb/mask bias into d_ws ============
__global__ __launch_bounds__(256)
void pack_all(const float* __restrict__ qkvw, const float* __restrict__ pw,
              const float* __restrict__ f1w, const float* __restrict__ f2w,
              const float* __restrict__ mask, const float* __restrict__ rpb,
              unsigned short* __restrict__ o, unsigned short* __restrict__ ob)
{
    if (blockIdx.x < 216) {
        const int t = blockIdx.x * 256 + threadIdx.x; // 0..55295
        const int lane = t & 63, f = t >> 6;
        const int ln = lane & 15, ko = (lane >> 4) * 8;
        const float* src;
        if (f < 216) {
            const int h = f / 36, r = f - h * 36, nf = r / 6, kf = r - nf * 6;
            src = qkvw + (size_t)((nf >> 1) * 192 + h * 32 + (nf & 1) * 16 + ln) * 192 + kf * 32 + ko;
        } else if (f < 288) {
            const int g = f - 216, h = g / 12, nf = g - h * 12;
            src = pw + (size_t)(nf * 16 + ln) * 192 + h * 32 + ko;
        } else {
            const int g = f - 288;
            const int c = g / 24, r24 = g - c * 24;
            if (r24 < 12) {
                const int nf = r24 / 6, kf = r24 - nf * 6;
                src = f1w + (size_t)(c * 32 + nf * 16 + ln) * 192 + kf * 32 + ko;
            } else {
                const int nf = r24 - 12;
                src = f2w + (size_t)(nf * 16 + ln) * 768 + c * 32 + ko;
            }
        }
        *(s16x8*)(o + (size_t)t * 8) = cvt8(*(const float4*)src, *(const float4*)(src + 4));
    } else {
        const int bid = blockIdx.x - 216;            // 0..383
        const int wi = bid / 6, h = bid - wi * 6;
        for (int t = threadIdx.x; t < 49 * 64; t += 256) {
            const int n = t >> 6, mm = t & 63;
            const int ln = mm >> 2, nf = mm & 3;
            const int m = nf * 16 + ln;
            float v = -100.0f;
            if (m < 49) {
                const int p1 = n / 7, q1 = n - p1 * 7, p2 = m / 7, q2 = m - p2 * 7;
                const int ridx = (p1 - p2 + 6) * 13 + (q1 - q2 + 6);
                v = rpb[ridx * 6 + h] + mask[(size_t)wi * 2401 + n * 49 + m];
            }
            ob[(size_t)(wi * 6 + h) * 3136 + t] = f2bf(v);
        }
    }
}

// ============ Kernel A: LN1 + shift/window + MFMA attention + proj + residual ============
__global__ __launch_bounds__(256, 3)
void swin_attn(const float* __restrict__ x, const float* __restrict__ g1,
               const float* __restrict__ b1, const unsigned short* __restrict__ wp,
               const unsigned short* __restrict__ bias_g,
               const float* __restrict__ qkvb, const float* __restrict__ pb,
               float* __restrict__ y)
{
    __shared__ __align__(16) unsigned short q_[64][40];      // 5120 (wave-private rows)
    __shared__ __align__(16) unsigned short o_[64][40];      // 5120 (wave-private rows)
    __shared__ __align__(16) unsigned short k2_[2][64][40];  // 10240 (cross-wave, dbuf)
    __shared__ __align__(16) unsigned short vt2_[2][32][72]; // 9216 (cross-wave, dbuf)
    __shared__ __align__(16) unsigned short p_[64][72];      // 9216 (wave-private rows)
    // total 38912 B

    const s16x8* wv = (const s16x8*)wp;
    const int w  = blockIdx.x;
    const int bb = w >> 6, wi = w & 63;
    const int wh = wi >> 3, ww = wi & 7;
    const int tid = threadIdx.x, lane = tid & 63, wave = tid >> 6;
    const int ln = lane & 15, hi = lane >> 4, ko = hi * 8, ro = hi * 4;
    const int m0 = wave * 16;

    // ---- LN1 fully in registers ----
    s16x8 xa[6];
    {
        const int t = m0 + ln;
        const int p = t / 7, q7 = t - p * 7;
        int i2 = wh * 7 + p + 3;  if (i2 >= 56) i2 -= 56;
        int j2 = ww * 7 + q7 + 3; if (j2 >= 56) j2 -= 56;
        const float* xr = x + ((size_t)(bb * 56 + i2) * 56 + j2) * 192;
        ln_frag(xr, g1, b1, hi, xa);
        if (t >= 49) {
            #pragma unroll
            for (int k = 0; k < 6; ++k) xa[k] = s16x8{0,0,0,0,0,0,0,0};
        }
    }

    // QKV for head hh into buffer hh&1 (q_ single: wave-private, consumed before next write)
    auto qkv_head = [&](int hh) {
        const s16x8* wq = wv + ((size_t)(hh * 36) << 6);
        #pragma unroll
        for (int nf = 0; nf < 6; ++nf) {
            s16x8 bf6[6];
            #pragma unroll
            for (int kf = 0; kf < 6; ++kf) bf6[kf] = wq[(nf * 6 + kf) * 64 + lane];
            f32x4 a = f32x4{0.f,0.f,0.f,0.f};
            #pragma unroll
            for (int kf = 0; kf < 6; ++kf)
                a = __builtin_amdgcn_mfma_f32_16x16x32_bf16(xa[kf], bf6[kf], a, 0, 0, 0);
            const int col = nf * 16 + ln;
            if (nf < 2) {
                const float bq = qkvb[hh*32 + col];
                const unsigned lo = pk2((a[0]+bq)*cSCALE, (a[1]+bq)*cSCALE);
                const unsigned hh2 = pk2((a[2]+bq)*cSCALE, (a[3]+bq)*cSCALE);
                q_[m0+ro+0][col] = (unsigned short)lo;  q_[m0+ro+1][col] = (unsigned short)(lo >> 16);
                q_[m0+ro+2][col] = (unsigned short)hh2; q_[m0+ro+3][col] = (unsigned short)(hh2 >> 16);
            } else if (nf < 4) {
                const float bk = qkvb[192 + hh*32 + col - 32];
                const unsigned lo = pk2(a[0]+bk, a[1]+bk), hh2 = pk2(a[2]+bk, a[3]+bk);
                k2_[hh&1][m0+ro+0][col-32] = (unsigned short)lo;  k2_[hh&1][m0+ro+1][col-32] = (unsigned short)(lo >> 16);
                k2_[hh&1][m0+ro+2][col-32] = (unsigned short)hh2; k2_[hh&1][m0+ro+3][col-32] = (unsigned short)(hh2 >> 16);
            } else {
                const float bv = qkvb[384 + hh*32 + col - 64];
                const unsigned lo = pk2(a[0]+bv, a[1]+bv), hh2 = pk2(a[2]+bv, a[3]+bv);
                vt2_[hh&1][col-64][m0+ro+0] = (unsigned short)lo;  vt2_[hh&1][col-64][m0+ro+1] = (unsigned short)(lo >> 16);
                vt2_[hh&1][col-64][m0+ro+2] = (unsigned short)hh2; vt2_[hh&1][col-64][m0+ro+3] = (unsigned short)(hh2 >> 16);
            }
        }
    };

    qkv_head(0);

    f32x4 accp[12];
    #pragma unroll
    for (int i = 0; i < 12; ++i) accp[i] = f32x4{0.f,0.f,0.f,0.f};

    // bias prefetch for head 0 (clamped rows; garbage rows discarded at epilogue)
    uint2 bb4[4];
    {
        const unsigned short* bg = bias_g + (size_t)(wi * 6) * 3136;
        #pragma unroll
        for (int i = 0; i < 4; ++i) {
            const int nc = min(m0 + ro + i, 48);
            bb4[i] = *(const uint2*)(bg + nc * 64 + ln * 4);
        }
    }

    for (int h = 0; h < 6; ++h) {
        __syncthreads();   // k2_/vt2_[h&1] visible to all waves

        // ---- S = Q @ K^T + fused bias (mask baked); softmax without max-reduce ----
        f32x4 s4[4];
        {
            const s16x8 aq = *(const s16x8*)&q_[m0 + ln][ko];
            #pragma unroll
            for (int nf = 0; nf < 4; ++nf) {
                const s16x8 bk = *(const s16x8*)&k2_[h & 1][nf * 16 + ln][ko];
                s4[nf] = __builtin_amdgcn_mfma_f32_16x16x32_bf16(aq, bk, f32x4{0.f,0.f,0.f,0.f}, 0, 0, 0);
            }
        }
        float inv4[4];
        #pragma unroll
        for (int i = 0; i < 4; ++i) {
            const int n = m0 + ro + i;
            const uint2 u = bb4[i];
            const float e0 = __expf(s4[0][i] + bf2f((unsigned short)(u.x)));
            const float e1 = __expf(s4[1][i] + bf2f((unsigned short)(u.x >> 16)));
            const float e2 = __expf(s4[2][i] + bf2f((unsigned short)(u.y)));
            const float e3 = __expf(s4[3][i] + bf2f((unsigned short)(u.y >> 16)));
            float ssum = (e0 + e1) + (e2 + e3);
            #pragma unroll
            for (int o = 1; o < 16; o <<= 1) ssum += __shfl_xor(ssum, o);
            inv4[i] = 1.0f / ssum;
            const unsigned plo = pk2(e0, e1), phi = pk2(e2, e3);
            p_[n][     ln] = (unsigned short)plo;
            p_[n][16 + ln] = (unsigned short)(plo >> 16);
            p_[n][32 + ln] = (unsigned short)phi;
            p_[n][48 + ln] = (unsigned short)(phi >> 16);
        }

        // ---- prefetch next head's bias (hidden under PV + QKV + proj) ----
        {
            const int hn = (h < 5) ? h + 1 : 5;
            const unsigned short* bg = bias_g + (size_t)(wi * 6 + hn) * 3136;
            #pragma unroll
            for (int i = 0; i < 4; ++i) {
                const int nc = min(m0 + ro + i, 48);
                bb4[i] = *(const uint2*)(bg + nc * 64 + ln * 4);
            }
        }

        // ---- O = P @ V (unnormalized), scale by inv4 on store -> o_ ----
        f32x4 o2[2];
        o2[0] = f32x4{0.f,0.f,0.f,0.f}; o2[1] = f32x4{0.f,0.f,0.f,0.f};
        #pragma unroll
        for (int kf = 0; kf < 2; ++kf) {
            const s16x8 ap = *(const s16x8*)&p_[m0 + ln][kf * 32 + ko];
            #pragma unroll
            for (int nf = 0; nf < 2; ++nf) {
                const s16x8 bv = *(const s16x8*)&vt2_[h & 1][nf * 16 + ln][kf * 32 + ko];
                o2[nf] = __builtin_amdgcn_mfma_f32_16x16x32_bf16(ap, bv, o2[nf], 0, 0, 0);
            }
        }
        #pragma unroll
        for (int nf = 0; nf < 2; ++nf) {
            const int col = nf * 16 + ln;
            const unsigned lo = pk2(o2[nf][0] * inv4[0], o2[nf][1] * inv4[1]);
            const unsigned hh2 = pk2(o2[nf][2] * inv4[2], o2[nf][3] * inv4[3]);
            o_[m0+ro+0][col] = (unsigned short)lo;  o_[m0+ro+1][col] = (unsigned short)(lo >> 16);
            o_[m0+ro+2][col] = (unsigned short)hh2; o_[m0+ro+3][col] = (unsigned short)(hh2 >> 16);
        }

        // ---- QKV for next head into other buffer (overlaps this head's tail) ----
        if (h < 5) qkv_head(h + 1);

        // ---- proj partial (o_ wave-private) ----
        {
            const s16x8 ao = *(const s16x8*)&o_[m0 + ln][ko];
            const s16x8* wpj = wv + ((size_t)(216 + h * 12) << 6);
            #pragma unroll
            for (int half = 0; half < 2; ++half) {
                s16x8 bf6[6];
                #pragma unroll
                for (int nf = 0; nf < 6; ++nf) bf6[nf] = wpj[(half * 6 + nf) * 64 + lane];
                #pragma unroll
                for (int nf = 0; nf < 6; ++nf)
                    accp[half * 6 + nf] = __builtin_amdgcn_mfma_f32_16x16x32_bf16(
                        ao, bf6[nf], accp[half * 6 + nf], 0, 0, 0);
            }
        }
    }

    // ---- Epilogue: + proj bias + residual, scatter to shifted coords ----
    #pragma unroll
    for (int i = 0; i < 4; ++i) {
        const int n = m0 + ro + i;
        if (n < 49) {
            const int p = n / 7, q7 = n - p * 7;
            int i2 = wh * 7 + p + 3;  if (i2 >= 56) i2 -= 56;
            int j2 = ww * 7 + q7 + 3; if (j2 >= 56) j2 -= 56;
            const size_t base = ((size_t)(bb * 56 + i2) * 56 + j2) * 192;
            #pragma unroll
            for (int nf = 0; nf < 12; ++nf) {
                const int col = nf * 16 + ln;
                y[base + col] = x[base + col] + pb[col] + accp[nf][i];
            }
        }
    }
}

// stage one 24 KB chunk (fc1_c 12K + fc2_c 12K) into LDS with 256 threads, async (6 GLDS/thread)
__device__ __forceinline__ void stage24k(const unsigned short* __restrict__ wp, int c,
                                         unsigned short* dst, int tid) {
    const unsigned short* g = wp + (((size_t)(288 + c * 24)) << 9) + tid * 8;
    unsigned short* l = dst + tid * 8;
    #pragma unroll
    for (int i = 0; i < 6; ++i)
        GLDS16(g + i * 2048, l + i * 2048);
}

// ===== Kernel B: LN2 + fc1 + GELU + fc2 + residual; 32 rows/wave =====
__global__ __launch_bounds__(256, 2)
void swin_mlp(const float* __restrict__ g2, const float* __restrict__ b2,
              const unsigned short* __restrict__ wp,
              const float* __restrict__ f1b, const float* __restrict__ f2b,
              float* __restrict__ y)
{
    __shared__ __align__(16) unsigned short wbuf[2][12288]; // 49152 B (fc1|fc2 chunk, dbuf)
    __shared__ __align__(16) unsigned short hb[128][40];    // 10240 B (rows wave-private)
    __shared__ float f1b_l[768];                            // 3072 B
    __shared__ float f2b_l[192];                            // 768 B

    const int tid = threadIdx.x, lane = tid & 63, wave = tid >> 6;
    const int ln = lane & 15, hi = lane >> 4, ko = hi * 8, ro = hi * 4;
    const int m0 = wave * 32;                    // 0,32,64,96
    const size_t r0 = (size_t)blockIdx.x * 128;

    for (int t = tid; t < 768; t += 256) f1b_l[t] = f1b[t];
    for (int t = tid; t < 192; t += 256) f2b_l[t] = f2b[t];

    s16x8 xa[12];
    ln_frag(y + (r0 + m0 +      ln) * 192, g2, b2, hi, xa);
    ln_frag(y + (r0 + m0 + 16 + ln) * 192, g2, b2, hi, xa + 6);

    stage24k(wp, 0, wbuf[0], tid);
    stage24k(wp, 1, wbuf[1], tid);
    asm volatile("s_waitcnt lgkmcnt(0)" ::: "memory");

    f32x4 acc2[24];
    #pragma unroll
    for (int i = 0; i < 24; ++i) acc2[i] = f32x4{0.f,0.f,0.f,0.f};

    for (int c = 0; c < 24; ++c) {
        if (c == 23) asm volatile("s_waitcnt vmcnt(0)" ::: "memory");
        else         asm volatile("s_waitcnt vmcnt(6)" ::: "memory");
        __builtin_amdgcn_s_barrier();

        const s16x8* wb = (const s16x8*)wbuf[c & 1];
        f32x4 acc1[4];
        #pragma unroll
        for (int i = 0; i < 4; ++i) acc1[i] = f32x4{0.f,0.f,0.f,0.f};
        #pragma unroll
        for (int kf = 0; kf < 6; ++kf) {
            #pragma unroll
            for (int nf = 0; nf < 2; ++nf) {
                const s16x8 b = wb[(nf * 6 + kf) * 64 + lane];
                acc1[nf*2+0] = __builtin_amdgcn_mfma_f32_16x16x32_bf16(xa[kf],     b, acc1[nf*2+0], 0, 0, 0);
                acc1[nf*2+1] = __builtin_amdgcn_mfma_f32_16x16x32_bf16(xa[6 + kf], b, acc1[nf*2+1], 0, 0, 0);
            }
        }
        #pragma unroll
        for (int nf = 0; nf < 2; ++nf) {
            const int col = nf * 16 + ln;
            const float bias = f1b_l[c * 32 + col];
            #pragma unroll
            for (int rs = 0; rs < 2; ++rs) {
                const f32x4 a = acc1[nf*2+rs];
                const int rb = m0 + rs * 16 + ro;
                const unsigned lo = pk2(gelu_f(a[0] + bias), gelu_f(a[1] + bias));
                const unsigned hh2 = pk2(gelu_f(a[2] + bias), gelu_f(a[3] + bias));
                hb[rb+0][col] = (unsigned short)lo;  hb[rb+1][col] = (unsigned short)(lo >> 16);
                hb[rb+2][col] = (unsigned short)hh2; hb[rb+3][col] = (unsigned short)(hh2 >> 16);
            }
        }
        const s16x8 ah0 = *(const s16x8*)&hb[m0 +      ln][ko];
        const s16x8 ah1 = *(const s16x8*)&hb[m0 + 16 + ln][ko];
        #pragma unroll
        for (int nf = 0; nf < 12; ++nf) {
            const s16x8 b = wb[(12 + nf) * 64 + lane];
            acc2[nf*2+0] = __builtin_amdgcn_mfma_f32_16x16x32_bf16(ah0, b, acc2[nf*2+0], 0, 0, 0);
            acc2[nf*2+1] = __builtin_amdgcn_mfma_f32_16x16x32_bf16(ah1, b, acc2[nf*2+1], 0, 0, 0);
        }

        if (c < 23) {
            __builtin_amdgcn_s_barrier();
            if (c < 22) stage24k(wp, c + 2, wbuf[c & 1], tid);
        }
    }

    #pragma unroll
    for (int rs = 0; rs < 2; ++rs) {
        #pragma unroll
        for (int i = 0; i < 4; ++i) {
            const int row = m0 + rs * 16 + ro + i;
            float* yp = y + (r0 + row) * 192;
            #pragma unroll
            for (int nf = 0; nf < 12; ++nf) {
                const int col = nf * 16 + ln;
                yp[col] = yp[col] + f2b_l[col] + acc2[nf*2+rs][i];
            }
        }
    }
}

extern "C" void kernel_launch(void* const* d_in, const int* in_sizes, int n_in,
                              void* d_out, int out_size, void* d_ws, size_t ws_size,
                              hipStream_t stream) {
    (void)in_sizes; (void)n_in; (void)ws_size; (void)out_size;
    const float* x    = (const float*)d_in[0];
    const float* mask = (const float*)d_in[1];
    const float* g1   = (const float*)d_in[2];
    const float* b1   = (const float*)d_in[3];
    const float* qkvw = (const float*)d_in[4];
    const float* qkvb = (const float*)d_in[5];
    const float* rpb  = (const float*)d_in[6];
    const float* pw   = (const float*)d_in[7];
    const float* pb   = (const float*)d_in[8];
    const float* g2   = (const float*)d_in[9];
    const float* b2   = (const float*)d_in[10];
    const float* f1w  = (const float*)d_in[11];
    const float* f1b  = (const float*)d_in[12];
    const float* f2w  = (const float*)d_in[13];
    const float* f2b  = (const float*)d_in[14];
    float* y = (float*)d_out;
    unsigned short* wpk  = (unsigned short*)d_ws;   // 884,736 B
    unsigned short* bias = wpk + 442368;            // 2,408,448 B -> ~3.3 MB total

    pack_all<<<dim3(600), dim3(256), 0, stream>>>(qkvw, pw, f1w, f2w, mask, rpb, wpk, bias);
    swin_attn<<<dim3(64 * 64), dim3(256), 0, stream>>>(
        x, g1, b1, wpk, bias, qkvb, pb, y);
    swin_mlp<<<dim3(1568), dim3(256), 0, stream>>>(
        g2, b2, wpk, f1b, f2b, y);
}